// Round 7
// baseline (643.108 us; speedup 1.0000x reference)
//
#include <hip/hip_runtime.h>

// ConvMGSA on MI355X. Inputs/outputs FLOAT32; intermediates bf16.
// N=4 G=8 CIN=COUT=256 K=3 M=4 D=64 H=W=32 HW=1024.
//
// R7: attention via packed v_dot2_f32_bf16 (2 MACs/inst, no unpack):
//  - QK: q/k stay packed bf16 pairs; 4 fdot2 per 16B fragment
//  - V GEMM stores V TRANSPOSED [p][m*512+d*8+e] so AV contracts over
//    e-contiguous pairs; attn weights packed bf16 in LDS [32][10][8]
//  - __has_builtin fallback to unpack path (no compile risk)

typedef unsigned short u16;
typedef unsigned int u32;
typedef __attribute__((ext_vector_type(8))) short bf16x8;
typedef __attribute__((ext_vector_type(4))) float f32x4;

__device__ __forceinline__ u32 fbits(float f) { u32 x; __builtin_memcpy(&x, &f, 4); return x; }
__device__ __forceinline__ float bf2f(u32 v) {
    u32 x = v << 16; float f; __builtin_memcpy(&f, &x, 4); return f;
}
__device__ __forceinline__ u16 f2bf(float f) {
    u32 x = fbits(f);
    u32 r = x + 0x7fffu + ((x >> 16) & 1u);
    return (u16)(r >> 16);
}
__device__ __forceinline__ u32 pack2bf(float a, float b) {
    return __builtin_amdgcn_perm(fbits(b) + 0x8000u, fbits(a) + 0x8000u, 0x07060302u);
}
__device__ __forceinline__ u16 bfr(float f) { return (u16)((fbits(f) + 0x8000u) >> 16); }

__device__ __forceinline__ void unpack8(uint4 u, float* o) {
    o[0] = bf2f(u.x & 0xffff); o[1] = bf2f(u.x >> 16);
    o[2] = bf2f(u.y & 0xffff); o[3] = bf2f(u.y >> 16);
    o[4] = bf2f(u.z & 0xffff); o[5] = bf2f(u.z >> 16);
    o[6] = bf2f(u.w & 0xffff); o[7] = bf2f(u.w >> 16);
}
__device__ __forceinline__ void ld8bf(const u16* p, float* o) { unpack8(*(const uint4*)p, o); }
__device__ __forceinline__ void ld8f(const float* p, float* o) {
    float4 a = *(const float4*)p, b = *(const float4*)(p + 4);
    o[0] = a.x; o[1] = a.y; o[2] = a.z; o[3] = a.w;
    o[4] = b.x; o[5] = b.y; o[6] = b.z; o[7] = b.w;
}
__device__ __forceinline__ void st4bf(u16* p, const float* v) {
    ushort4 s; s.x = f2bf(v[0]); s.y = f2bf(v[1]); s.z = f2bf(v[2]); s.w = f2bf(v[3]);
    *(ushort4*)p = s;
}

// packed bf16 pair dot: c += a0*b0 + a1*b1
#if defined(__has_builtin)
#if __has_builtin(__builtin_amdgcn_fdot2_f32_bf16)
#define HAVE_BFDOT 1
#endif
#endif
#ifdef HAVE_BFDOT
typedef __attribute__((ext_vector_type(2))) __bf16 v2bf;
__device__ __forceinline__ float dot2bf(u32 a, u32 b, float c) {
    return __builtin_amdgcn_fdot2_f32_bf16(__builtin_bit_cast(v2bf, a),
                                           __builtin_bit_cast(v2bf, b), c, false);
}
#else
__device__ __forceinline__ float dot2bf(u32 a, u32 b, float c) {
    return c + bf2f(a & 0xffff) * bf2f(b & 0xffff) + bf2f(a >> 16) * bf2f(b >> 16);
}
#endif
__device__ __forceinline__ float dot8bf(uint4 a, uint4 b, float c) {
    c = dot2bf(a.x, b.x, c); c = dot2bf(a.y, b.y, c);
    c = dot2bf(a.z, b.z, c); c = dot2bf(a.w, b.w, c);
    return c;
}

// ================= MFMA GEMM: C[o][p] = sum_i W[g][o][i] * B[i][p] =================
// BMODE: 0=f32 i-major, 1=bf16 i-major, 2=bf16 pixel-major
// OUTMODE: 0=bf16 pixel-major [p][g*256+o], 1=bf16 channel-major +bias(+relu),
//          2=bf16 pixel-major V-TRANSPOSED [p][m*512+d*8+e] (e = this group)
template<int BMODE, int OUTMODE, int RELU>
__global__ __launch_bounds__(256) void gemm_kernel(
    const float* __restrict__ A, const void* __restrict__ B,
    const float* __restrict__ bias, u16* __restrict__ out) {
    __shared__ __align__(16) char smem[OUTMODE == 1 ? 64 * 132 * 4 : 20480];
    u16* Al = (u16*)smem;              // [128][40] bf16  (o, k)
    u16* Bl = (u16*)(smem + 10240);    // [128][40] bf16  (p, k)
    float* Cl = (float*)smem;          // [64][132] f32   (epilogue transpose)

    const int tid = threadIdx.x;
    const int pt = blockIdx.x, ot = blockIdx.y, ng = blockIdx.z;
    const int n = ng >> 3, g = ng & 7;
    const int p0 = pt << 7, o0 = ot << 7;
    const float* Ag = A + (size_t)g * 65536;

    const int l = tid & 63, w = tid >> 6;
    const int mq = w >> 1;
    const int mw = mq << 6, nw = (w & 1) << 6;
    const int lrow = l & 15, lk = (l >> 4) << 3;

    f32x4 acc[4][4];
    #pragma unroll
    for (int i = 0; i < 4; i++)
        #pragma unroll
        for (int j = 0; j < 4; j++) acc[i][j] = (f32x4){0.f, 0.f, 0.f, 0.f};

    for (int k0 = 0; k0 < 256; k0 += 32) {
        {
            const int r = tid >> 1, cb = (tid & 1) << 4;
            const float* src = Ag + (size_t)(o0 + r) * 256 + k0 + cb;
            u32* dst = (u32*)&Al[r * 40 + cb];
            #pragma unroll
            for (int q = 0; q < 4; q++) {
                float4 f = *(const float4*)(src + q * 4);
                dst[q * 2]     = pack2bf(f.x, f.y);
                dst[q * 2 + 1] = pack2bf(f.z, f.w);
            }
        }
        if (BMODE == 2) {
            const int r = tid >> 1, cb = (tid & 1) << 4;
            const u16* src = (const u16*)B + (size_t)(n * 1024 + p0 + r) * 2048 + g * 256 + k0 + cb;
            *(uint4*)&Bl[r * 40 + cb]     = *(const uint4*)src;
            *(uint4*)&Bl[r * 40 + cb + 8] = *(const uint4*)(src + 8);
        } else {
            const int kr = tid >> 3, pc = (tid & 7) << 4;
            if (BMODE == 0) {
                const float* src = (const float*)B + (size_t)(ng * 256 + k0 + kr) * 1024 + p0 + pc;
                #pragma unroll
                for (int q = 0; q < 4; q++) {
                    float4 f = *(const float4*)(src + q * 4);
                    Bl[(pc + q * 4 + 0) * 40 + kr] = bfr(f.x);
                    Bl[(pc + q * 4 + 1) * 40 + kr] = bfr(f.y);
                    Bl[(pc + q * 4 + 2) * 40 + kr] = bfr(f.z);
                    Bl[(pc + q * 4 + 3) * 40 + kr] = bfr(f.w);
                }
            } else {
                const u16* src = (const u16*)B + (size_t)(ng * 256 + k0 + kr) * 1024 + p0 + pc;
                uint4 v0 = *(const uint4*)src;
                uint4 v1 = *(const uint4*)(src + 8);
                u16 tmp[16];
                *(uint4*)&tmp[0] = v0; *(uint4*)&tmp[8] = v1;
                #pragma unroll
                for (int u = 0; u < 16; u++) Bl[(pc + u) * 40 + kr] = tmp[u];
            }
        }
        __syncthreads();
        bf16x8 af[4], bfg[4];
        #pragma unroll
        for (int i = 0; i < 4; i++) af[i]  = *(const bf16x8*)&Al[(mw + i * 16 + lrow) * 40 + lk];
        #pragma unroll
        for (int j = 0; j < 4; j++) bfg[j] = *(const bf16x8*)&Bl[(nw + j * 16 + lrow) * 40 + lk];
        #pragma unroll
        for (int i = 0; i < 4; i++)
            #pragma unroll
            for (int j = 0; j < 4; j++)
                acc[i][j] = __builtin_amdgcn_mfma_f32_16x16x32_bf16(af[i], bfg[j], acc[i][j], 0, 0, 0);
        __syncthreads();
    }

    if (OUTMODE == 0) {
        #pragma unroll
        for (int i = 0; i < 4; i++) {
            const int orow = o0 + mw + i * 16 + ((l >> 4) << 2);
            #pragma unroll
            for (int j = 0; j < 4; j++) {
                const int p = p0 + nw + j * 16 + lrow;
                float v4[4] = { acc[i][j].x, acc[i][j].y, acc[i][j].z, acc[i][j].w };
                st4bf(out + (size_t)(n * 1024 + p) * 2048 + g * 256 + orow, v4);
            }
        }
    } else if (OUTMODE == 2) {
        // V transposed: idx = p*2048 + m*512 + d*8 + e  (o = m*64+d, e = g)
        #pragma unroll
        for (int i = 0; i < 4; i++) {
            const int o = o0 + mw + i * 16 + ((l >> 4) << 2);
            const int m = o >> 6, d = o & 63;
            #pragma unroll
            for (int j = 0; j < 4; j++) {
                const int p = p0 + nw + j * 16 + lrow;
                u16* dst = out + (size_t)(n * 1024 + p) * 2048 + m * 512 + d * 8 + g;
                dst[0]  = f2bf(acc[i][j].x);
                dst[8]  = f2bf(acc[i][j].y);
                dst[16] = f2bf(acc[i][j].z);
                dst[24] = f2bf(acc[i][j].w);
            }
        }
    } else {
        for (int ph = 0; ph < 2; ph++) {
            __syncthreads();
            if (mq == ph) {
                #pragma unroll
                for (int i = 0; i < 4; i++) {
                    const int rl = i * 16 + ((l >> 4) << 2);
                    #pragma unroll
                    for (int j = 0; j < 4; j++) {
                        const int c = nw + j * 16 + lrow;
                        Cl[(rl    ) * 132 + c] = acc[i][j].x;
                        Cl[(rl + 1) * 132 + c] = acc[i][j].y;
                        Cl[(rl + 2) * 132 + c] = acc[i][j].z;
                        Cl[(rl + 3) * 132 + c] = acc[i][j].w;
                    }
                }
            }
            __syncthreads();
            {
                const int row = tid >> 2, pc = (tid & 3) << 5;
                const int og = o0 + ph * 64 + row;
                const float bb = bias ? bias[g * 256 + og] : 0.f;
                u32 pk[16];
                #pragma unroll
                for (int q = 0; q < 8; q++) {
                    float4 f = *(const float4*)&Cl[row * 132 + pc + q * 4];
                    float a0 = f.x + bb, a1 = f.y + bb, a2 = f.z + bb, a3 = f.w + bb;
                    if (RELU) {
                        a0 = fmaxf(a0, 0.f); a1 = fmaxf(a1, 0.f);
                        a2 = fmaxf(a2, 0.f); a3 = fmaxf(a3, 0.f);
                    }
                    pk[q * 2]     = pack2bf(a0, a1);
                    pk[q * 2 + 1] = pack2bf(a2, a3);
                }
                u16* dst = out + (size_t)(ng * 256 + og) * 1024 + p0 + pc;
                #pragma unroll
                for (int q = 0; q < 4; q++) *(uint4*)(dst + q * 8) = *(uint4*)&pk[q * 4];
            }
        }
    }
}

// ---------------- attention: one block per (n, pixel), packed-dot ----------------
// vtt is V-transposed [p][m*512+d*8+e]; av output standard pixel-major.
__global__ __launch_bounds__(256) void attn_kernel(
    const u16* __restrict__ qt, const u16* __restrict__ kt,
    const u16* __restrict__ vtt, const float* __restrict__ hm,
    const float* __restrict__ wm, u16* __restrict__ av) {
    __shared__ u16 attn_b[32][10][8];    // [m*8+g][ij(padded)][e] bf16
    const int tid = threadIdx.x;
    const int p = blockIdx.x, n = blockIdx.y;
    const int ph = p >> 5, pw = p & 31;
    const size_t nimg = (size_t)n * 1024;

    int npix[9]; unsigned inb = 0;
    #pragma unroll
    for (int ij = 0; ij < 9; ij++) {
        int hs = ph + ij / 3 - 1, ws = pw + ij % 3 - 1;
        npix[ij] = hs * 32 + ws;
        if (((unsigned)hs < 32u) && ((unsigned)ws < 32u)) inb |= (1u << ij);
    }

    const int e_th = tid & 7;
    const int row = tid >> 3, g_th = row & 7, m_th = row >> 3;
    const int cbase = e_th * 256 + m_th * 64;
    const u16* qp = qt + (nimg + p) * 2048 + g_th * 256 + m_th * 64;
    const float* relbase = (e_th < 4) ? (hm + (size_t)cbase * 3)
                                      : (wm + (size_t)(cbase - 1024) * 3);

    float sc[9] = {};
    float qrel[3] = {};
    if (inb == 0x1ffu) {
        for (int c8 = 0; c8 < 8; c8++) {
            const uint4 qv = *(const uint4*)(qp + c8 * 8);
            uint4 kr[9];
            #pragma unroll
            for (int ij = 0; ij < 9; ij++)
                kr[ij] = *(const uint4*)(kt + (nimg + npix[ij]) * 2048 + cbase + c8 * 8);
            float q8[8];
            unpack8(qv, q8);
            #pragma unroll
            for (int t = 0; t < 6; t++) {
                float4 f = *(const float4*)(relbase + c8 * 24 + t * 4);
                int b = t * 4;   // rel index r = b..b+3 -> (d, comp) = (r/3, r%3)
                qrel[(b    ) % 3] += q8[(b    ) / 3] * f.x;
                qrel[(b + 1) % 3] += q8[(b + 1) / 3] * f.y;
                qrel[(b + 2) % 3] += q8[(b + 2) / 3] * f.z;
                qrel[(b + 3) % 3] += q8[(b + 3) / 3] * f.w;
            }
            #pragma unroll
            for (int ij = 0; ij < 9; ij++) sc[ij] = dot8bf(qv, kr[ij], sc[ij]);
        }
    } else {
        for (int c8 = 0; c8 < 8; c8++) {
            const uint4 qv = *(const uint4*)(qp + c8 * 8);
            float q8[8];
            unpack8(qv, q8);
            #pragma unroll
            for (int t = 0; t < 6; t++) {
                float4 f = *(const float4*)(relbase + c8 * 24 + t * 4);
                int b = t * 4;
                qrel[(b    ) % 3] += q8[(b    ) / 3] * f.x;
                qrel[(b + 1) % 3] += q8[(b + 1) / 3] * f.y;
                qrel[(b + 2) % 3] += q8[(b + 2) / 3] * f.z;
                qrel[(b + 3) % 3] += q8[(b + 3) / 3] * f.w;
            }
            for (int ij = 0; ij < 9; ij++) {
                if (inb & (1u << ij)) {
                    uint4 kv = *(const uint4*)(kt + (nimg + npix[ij]) * 2048 + cbase + c8 * 8);
                    sc[ij] = dot8bf(qv, kv, sc[ij]);
                }
            }
        }
    }
    #pragma unroll
    for (int ij = 0; ij < 9; ij++) {
        int idx = (e_th < 4) ? (ij / 3) : (ij % 3);
        sc[ij] += qrel[idx];
    }

    float mx = sc[0];
    #pragma unroll
    for (int ij = 1; ij < 9; ij++) mx = fmaxf(mx, sc[ij]);
    mx = fmaxf(mx, __shfl_xor(mx, 1)); mx = fmaxf(mx, __shfl_xor(mx, 2)); mx = fmaxf(mx, __shfl_xor(mx, 4));
    float sum = 0.f;
    #pragma unroll
    for (int ij = 0; ij < 9; ij++) { sc[ij] = __expf(sc[ij] - mx); sum += sc[ij]; }
    sum += __shfl_xor(sum, 1); sum += __shfl_xor(sum, 2); sum += __shfl_xor(sum, 4);
    const float rinv = 1.f / sum;
    #pragma unroll
    for (int ij = 0; ij < 9; ij++) attn_b[row][ij][e_th] = f2bf(sc[ij] * rinv);
    __syncthreads();

    // AV: thread owns (g,m,d0..d0+7); contract over e via packed pairs
    const int c0 = tid << 3;
    const int m_av = (c0 >> 6) & 3, d0 = c0 & 63;
    const int arow = m_av * 8 + (c0 >> 8);
    float acc[8] = {};
    for (int ij = 0; ij < 9; ij++) {
        if (!(inb & (1u << ij))) continue;
        const uint4 aw = *(const uint4*)&attn_b[arow][ij][0];     // 8 e as 4 pairs
        const u16* vb = vtt + (nimg + npix[ij]) * 2048 + m_av * 512 + d0 * 8;
        #pragma unroll
        for (int u = 0; u < 8; u++) {
            uint4 vv = *(const uint4*)(vb + u * 8);
            acc[u] = dot8bf(aw, vv, acc[u]);
        }
    }
    st4bf(av + (nimg + p) * 2048 + c0, acc);
    st4bf(av + (nimg + p) * 2048 + c0 + 4, acc + 4);
}

// ---------------- LN over d=64 of A+B; scramble-contiguous write ----------------
__global__ __launch_bounds__(256) void ln_kernel(
    const void* __restrict__ A, int aF32, const void* __restrict__ B, int bF32,
    const float* __restrict__ gamma, const float* __restrict__ beta,
    void* __restrict__ out, int outF32) {
    __shared__ float s[64][68];
    __shared__ float red[2][4][64];
    __shared__ float mu_s[64], rs_s[64], gam[64], bet[64];
    const int tid = threadIdx.x;
    const int pt = blockIdx.x, m = blockIdx.y, ng = blockIdx.z;
    const int n = ng >> 3, g = ng & 7;
    const int p0 = pt << 6;
    if (tid < 64) { gam[tid] = gamma[tid]; bet[tid] = beta[tid]; }

    const int sd = tid >> 2, sp = (tid & 3) << 4;
    {
        const size_t base = (size_t)((n * 8 + g) * 256 + m * 64 + sd) * 1024 + p0 + sp;
        #pragma unroll
        for (int half = 0; half < 2; half++) {
            float a8[8], b8[8];
            if (aF32) ld8f((const float*)A + base + half * 8, a8);
            else      ld8bf((const u16*)A + base + half * 8, a8);
            if (bF32) ld8f((const float*)B + base + half * 8, b8);
            else      ld8bf((const u16*)B + base + half * 8, b8);
            #pragma unroll
            for (int u = 0; u < 8; u++) s[sd][sp + half * 8 + u] = a8[u] + b8[u];
        }
    }
    __syncthreads();
    const int rp = tid & 63, rq = tid >> 6;
    float sm = 0.f, sq = 0.f;
    #pragma unroll
    for (int u = 0; u < 16; u++) { float v = s[rq * 16 + u][rp]; sm += v; sq += v * v; }
    red[0][rq][rp] = sm; red[1][rq][rp] = sq;
    __syncthreads();
    if (tid < 64) {
        float s2 = red[0][0][tid] + red[0][1][tid] + red[0][2][tid] + red[0][3][tid];
        float q2 = red[1][0][tid] + red[1][1][tid] + red[1][2][tid] + red[1][3][tid];
        float mu = s2 * (1.f / 64.f);
        float var = q2 * (1.f / 64.f) - mu * mu;
        mu_s[tid] = mu; rs_s[tid] = rsqrtf(var + 1e-5f);
    }
    __syncthreads();
    const int op = tid >> 2, od = (tid & 3) << 4;
    const float mu = mu_s[op], rs = rs_s[op];
    const size_t obase = (size_t)n * 2097152 + (size_t)(p0 + op) * 2048 + m * 512 + g * 64 + od;
    #pragma unroll
    for (int q4 = 0; q4 < 4; q4++) {
        float v4[4];
        #pragma unroll
        for (int u = 0; u < 4; u++) {
            int d = od + q4 * 4 + u;
            v4[u] = (s[d][op] - mu) * rs * gam[d] + bet[d];
        }
        if (outF32) {
            float4 f4; f4.x = v4[0]; f4.y = v4[1]; f4.z = v4[2]; f4.w = v4[3];
            *(float4*)((float*)out + obase + q4 * 4) = f4;
        } else {
            st4bf((u16*)out + obase + q4 * 4, v4);
        }
    }
}

extern "C" void kernel_launch(void* const* d_in, const int* in_sizes, int n_in,
                              void* d_out, int out_size, void* d_ws, size_t ws_size,
                              hipStream_t stream) {
    const float* x   = (const float*)d_in[0];
    const float* wq  = (const float*)d_in[1];
    const float* wk  = (const float*)d_in[2];
    const float* wv  = (const float*)d_in[3];
    const float* hm  = (const float*)d_in[4];
    const float* wm  = (const float*)d_in[5];
    const float* wc  = (const float*)d_in[6];
    const float* bc  = (const float*)d_in[7];
    const float* wf1 = (const float*)d_in[8];
    const float* bf1 = (const float*)d_in[9];
    const float* wf2 = (const float*)d_in[10];
    const float* bf2w = (const float*)d_in[11];
    const float* g1  = (const float*)d_in[12];
    const float* b1  = (const float*)d_in[13];
    const float* g2  = (const float*)d_in[14];
    const float* b2  = (const float*)d_in[15];
    char* ws = (char*)d_ws;
    u16* bufQ = (u16*)d_out;                     // bf16 scratch in d_out: q -> av -> ffn hidden
    u16* bufK = (u16*)(ws);                      // k -> y2 -> f
    u16* bufV = (u16*)(ws + 16777216);           // v(transposed) -> y3

    const dim3 gg(8, 2, 32), gb(256);
    gemm_kernel<0, 0, 0><<<gg, gb, 0, stream>>>(wq, x, nullptr, bufQ);
    gemm_kernel<0, 0, 0><<<gg, gb, 0, stream>>>(wk, x, nullptr, bufK);
    gemm_kernel<0, 2, 0><<<gg, gb, 0, stream>>>(wv, x, nullptr, bufV);
    attn_kernel<<<dim3(1024, 4), gb, 0, stream>>>(bufQ, bufK, bufV, hm, wm, bufQ);
    gemm_kernel<2, 1, 0><<<gg, gb, 0, stream>>>(wc, bufQ, bc, bufK);
    ln_kernel<<<dim3(16, 4, 32), gb, 0, stream>>>(x, 1, bufK, 0, g1, b1, bufV, 0);
    gemm_kernel<1, 1, 1><<<gg, gb, 0, stream>>>(wf1, bufV, bf1, bufQ);
    gemm_kernel<1, 1, 0><<<gg, gb, 0, stream>>>(wf2, bufQ, bf2w, bufK);
    ln_kernel<<<dim3(16, 4, 32), gb, 0, stream>>>(bufV, 0, bufK, 0, g2, b2, d_out, 1);
}

// Round 8
// 422.842 us; speedup vs baseline: 1.5209x; 1.5209x over previous
//
#include <hip/hip_runtime.h>

// ConvMGSA on MI355X. Inputs/outputs FLOAT32; intermediates bf16.
// N=4 G=8 CIN=COUT=256 K=3 M=4 D=64 H=W=32 HW=1024.
//
// R8: attention latency fix — dense LDS staging of K/V (coalesced 16B/lane
// global loads), bank-quad-engineered LDS layout [ij][e][m][64+8] (e-stride
// 296 u16 -> 8 disjoint quads), AV wave remap (wave=m) so V reads are
// broadcast-merged 1-cycle b128s. V GEMM reverted to standard layout
// (R7's transposed scatter store regressed).

typedef unsigned short u16;
typedef unsigned int u32;
typedef __attribute__((ext_vector_type(8))) short bf16x8;
typedef __attribute__((ext_vector_type(4))) float f32x4;

__device__ __forceinline__ u32 fbits(float f) { u32 x; __builtin_memcpy(&x, &f, 4); return x; }
__device__ __forceinline__ float bf2f(u32 v) {
    u32 x = v << 16; float f; __builtin_memcpy(&f, &x, 4); return f;
}
__device__ __forceinline__ u16 f2bf(float f) {
    u32 x = fbits(f);
    u32 r = x + 0x7fffu + ((x >> 16) & 1u);
    return (u16)(r >> 16);
}
__device__ __forceinline__ u32 pack2bf(float a, float b) {
    return __builtin_amdgcn_perm(fbits(b) + 0x8000u, fbits(a) + 0x8000u, 0x07060302u);
}
__device__ __forceinline__ u16 bfr(float f) { return (u16)((fbits(f) + 0x8000u) >> 16); }

__device__ __forceinline__ void unpack8(uint4 u, float* o) {
    o[0] = bf2f(u.x & 0xffff); o[1] = bf2f(u.x >> 16);
    o[2] = bf2f(u.y & 0xffff); o[3] = bf2f(u.y >> 16);
    o[4] = bf2f(u.z & 0xffff); o[5] = bf2f(u.z >> 16);
    o[6] = bf2f(u.w & 0xffff); o[7] = bf2f(u.w >> 16);
}
__device__ __forceinline__ void ld8bf(const u16* p, float* o) { unpack8(*(const uint4*)p, o); }
__device__ __forceinline__ void ld8f(const float* p, float* o) {
    float4 a = *(const float4*)p, b = *(const float4*)(p + 4);
    o[0] = a.x; o[1] = a.y; o[2] = a.z; o[3] = a.w;
    o[4] = b.x; o[5] = b.y; o[6] = b.z; o[7] = b.w;
}
__device__ __forceinline__ void st4bf(u16* p, const float* v) {
    ushort4 s; s.x = f2bf(v[0]); s.y = f2bf(v[1]); s.z = f2bf(v[2]); s.w = f2bf(v[3]);
    *(ushort4*)p = s;
}

#if defined(__has_builtin)
#if __has_builtin(__builtin_amdgcn_fdot2_f32_bf16)
#define HAVE_BFDOT 1
#endif
#endif
#ifdef HAVE_BFDOT
typedef __attribute__((ext_vector_type(2))) __bf16 v2bf;
__device__ __forceinline__ float dot2bf(u32 a, u32 b, float c) {
    return __builtin_amdgcn_fdot2_f32_bf16(__builtin_bit_cast(v2bf, a),
                                           __builtin_bit_cast(v2bf, b), c, false);
}
#else
__device__ __forceinline__ float dot2bf(u32 a, u32 b, float c) {
    return c + bf2f(a & 0xffff) * bf2f(b & 0xffff) + bf2f(a >> 16) * bf2f(b >> 16);
}
#endif
__device__ __forceinline__ float dot8bf(uint4 a, uint4 b, float c) {
    c = dot2bf(a.x, b.x, c); c = dot2bf(a.y, b.y, c);
    c = dot2bf(a.z, b.z, c); c = dot2bf(a.w, b.w, c);
    return c;
}

// ================= MFMA GEMM: C[o][p] = sum_i W[g][o][i] * B[i][p] =================
// BMODE: 0=f32 i-major, 1=bf16 i-major, 2=bf16 pixel-major
// OUTMODE: 0=bf16 pixel-major [p][g*256+o], 1=bf16 channel-major +bias(+relu)
template<int BMODE, int OUTMODE, int RELU>
__global__ __launch_bounds__(256) void gemm_kernel(
    const float* __restrict__ A, const void* __restrict__ B,
    const float* __restrict__ bias, u16* __restrict__ out) {
    __shared__ __align__(16) char smem[OUTMODE == 1 ? 64 * 132 * 4 : 20480];
    u16* Al = (u16*)smem;              // [128][40] bf16  (o, k)
    u16* Bl = (u16*)(smem + 10240);    // [128][40] bf16  (p, k)
    float* Cl = (float*)smem;          // [64][132] f32   (epilogue transpose)

    const int tid = threadIdx.x;
    const int pt = blockIdx.x, ot = blockIdx.y, ng = blockIdx.z;
    const int n = ng >> 3, g = ng & 7;
    const int p0 = pt << 7, o0 = ot << 7;
    const float* Ag = A + (size_t)g * 65536;

    const int l = tid & 63, w = tid >> 6;
    const int mq = w >> 1;
    const int mw = mq << 6, nw = (w & 1) << 6;
    const int lrow = l & 15, lk = (l >> 4) << 3;

    f32x4 acc[4][4];
    #pragma unroll
    for (int i = 0; i < 4; i++)
        #pragma unroll
        for (int j = 0; j < 4; j++) acc[i][j] = (f32x4){0.f, 0.f, 0.f, 0.f};

    for (int k0 = 0; k0 < 256; k0 += 32) {
        {
            const int r = tid >> 1, cb = (tid & 1) << 4;
            const float* src = Ag + (size_t)(o0 + r) * 256 + k0 + cb;
            u32* dst = (u32*)&Al[r * 40 + cb];
            #pragma unroll
            for (int q = 0; q < 4; q++) {
                float4 f = *(const float4*)(src + q * 4);
                dst[q * 2]     = pack2bf(f.x, f.y);
                dst[q * 2 + 1] = pack2bf(f.z, f.w);
            }
        }
        if (BMODE == 2) {
            const int r = tid >> 1, cb = (tid & 1) << 4;
            const u16* src = (const u16*)B + (size_t)(n * 1024 + p0 + r) * 2048 + g * 256 + k0 + cb;
            *(uint4*)&Bl[r * 40 + cb]     = *(const uint4*)src;
            *(uint4*)&Bl[r * 40 + cb + 8] = *(const uint4*)(src + 8);
        } else {
            const int kr = tid >> 3, pc = (tid & 7) << 4;
            if (BMODE == 0) {
                const float* src = (const float*)B + (size_t)(ng * 256 + k0 + kr) * 1024 + p0 + pc;
                #pragma unroll
                for (int q = 0; q < 4; q++) {
                    float4 f = *(const float4*)(src + q * 4);
                    Bl[(pc + q * 4 + 0) * 40 + kr] = bfr(f.x);
                    Bl[(pc + q * 4 + 1) * 40 + kr] = bfr(f.y);
                    Bl[(pc + q * 4 + 2) * 40 + kr] = bfr(f.z);
                    Bl[(pc + q * 4 + 3) * 40 + kr] = bfr(f.w);
                }
            } else {
                const u16* src = (const u16*)B + (size_t)(ng * 256 + k0 + kr) * 1024 + p0 + pc;
                uint4 v0 = *(const uint4*)src;
                uint4 v1 = *(const uint4*)(src + 8);
                u16 tmp[16];
                *(uint4*)&tmp[0] = v0; *(uint4*)&tmp[8] = v1;
                #pragma unroll
                for (int u = 0; u < 16; u++) Bl[(pc + u) * 40 + kr] = tmp[u];
            }
        }
        __syncthreads();
        bf16x8 af[4], bfg[4];
        #pragma unroll
        for (int i = 0; i < 4; i++) af[i]  = *(const bf16x8*)&Al[(mw + i * 16 + lrow) * 40 + lk];
        #pragma unroll
        for (int j = 0; j < 4; j++) bfg[j] = *(const bf16x8*)&Bl[(nw + j * 16 + lrow) * 40 + lk];
        #pragma unroll
        for (int i = 0; i < 4; i++)
            #pragma unroll
            for (int j = 0; j < 4; j++)
                acc[i][j] = __builtin_amdgcn_mfma_f32_16x16x32_bf16(af[i], bfg[j], acc[i][j], 0, 0, 0);
        __syncthreads();
    }

    if (OUTMODE == 0) {
        #pragma unroll
        for (int i = 0; i < 4; i++) {
            const int orow = o0 + mw + i * 16 + ((l >> 4) << 2);
            #pragma unroll
            for (int j = 0; j < 4; j++) {
                const int p = p0 + nw + j * 16 + lrow;
                float v4[4] = { acc[i][j].x, acc[i][j].y, acc[i][j].z, acc[i][j].w };
                st4bf(out + (size_t)(n * 1024 + p) * 2048 + g * 256 + orow, v4);
            }
        }
    } else {
        for (int ph = 0; ph < 2; ph++) {
            __syncthreads();
            if (mq == ph) {
                #pragma unroll
                for (int i = 0; i < 4; i++) {
                    const int rl = i * 16 + ((l >> 4) << 2);
                    #pragma unroll
                    for (int j = 0; j < 4; j++) {
                        const int c = nw + j * 16 + lrow;
                        Cl[(rl    ) * 132 + c] = acc[i][j].x;
                        Cl[(rl + 1) * 132 + c] = acc[i][j].y;
                        Cl[(rl + 2) * 132 + c] = acc[i][j].z;
                        Cl[(rl + 3) * 132 + c] = acc[i][j].w;
                    }
                }
            }
            __syncthreads();
            {
                const int row = tid >> 2, pc = (tid & 3) << 5;
                const int og = o0 + ph * 64 + row;
                const float bb = bias ? bias[g * 256 + og] : 0.f;
                u32 pk[16];
                #pragma unroll
                for (int q = 0; q < 8; q++) {
                    float4 f = *(const float4*)&Cl[row * 132 + pc + q * 4];
                    float a0 = f.x + bb, a1 = f.y + bb, a2 = f.z + bb, a3 = f.w + bb;
                    if (RELU) {
                        a0 = fmaxf(a0, 0.f); a1 = fmaxf(a1, 0.f);
                        a2 = fmaxf(a2, 0.f); a3 = fmaxf(a3, 0.f);
                    }
                    pk[q * 2]     = pack2bf(a0, a1);
                    pk[q * 2 + 1] = pack2bf(a2, a3);
                }
                u16* dst = out + (size_t)(ng * 256 + og) * 1024 + p0 + pc;
                #pragma unroll
                for (int q = 0; q < 4; q++) *(uint4*)(dst + q * 8) = *(uint4*)&pk[q * 4];
            }
        }
    }
}

// ---------------- attention: one block per (n, pixel), LDS-staged ----------------
// LDS layout for K/V: [ij][e][m][72] u16 (strides: ij 2368, e 296, m 72).
// q: [g][m][72]. All b128 accesses verified 16B-aligned; e/g-strided reads hit
// 8 disjoint bank quads (148 mod 32 = 20, cycle {0,20,8,28,16,4,24,12}).
__global__ __launch_bounds__(256) void attn_kernel(
    const u16* __restrict__ qt, const u16* __restrict__ kt,
    const u16* __restrict__ vt, const float* __restrict__ hm,
    const float* __restrict__ wm, u16* __restrict__ av) {
    __shared__ __align__(16) u16 kvb[9 * 2368];
    __shared__ __align__(16) u16 qb[2368];
    __shared__ float attn_s[32][73];
    const int tid = threadIdx.x;
    const int p = blockIdx.x, n = blockIdx.y;
    const int ph = p >> 5, pw = p & 31;
    const size_t nimg = (size_t)n * 1024;

    int npix[9]; unsigned inb = 0;
    #pragma unroll
    for (int ij = 0; ij < 9; ij++) {
        int hs = ph + ij / 3 - 1, ws = pw + ij % 3 - 1;
        npix[ij] = hs * 32 + ws;
        if (((unsigned)hs < 32u) && ((unsigned)ws < 32u)) inb |= (1u << ij);
    }

    // staging map: channel c = tid*8 -> (e=c>>8, m=(c>>6)&3, d=c&63)
    const int c_s = tid << 3;
    const int soff = (tid >> 5) * 296 + ((tid >> 3) & 3) * 72 + (tid & 7) * 8;

    // ---- stage q + K ----
    *(uint4*)&qb[soff] = *(const uint4*)(qt + (nimg + p) * 2048 + c_s);
    #pragma unroll
    for (int ij = 0; ij < 9; ij++)
        if (inb & (1u << ij))
            *(uint4*)&kvb[ij * 2368 + soff] =
                *(const uint4*)(kt + (nimg + npix[ij]) * 2048 + c_s);
    __syncthreads();

    // ---- QK: thread (row=m*8+g, e) ----
    const int e_th = tid & 7;
    const int row = tid >> 3, g_th = row & 7, m_th = row >> 3;
    const int qoff = g_th * 296 + m_th * 72;
    const int koff = e_th * 296 + m_th * 72;
    const int cbase = e_th * 256 + m_th * 64;
    const float* relbase = (e_th < 4) ? (hm + (size_t)cbase * 3)
                                      : (wm + (size_t)(cbase - 1024) * 3);

    float sc[9] = {};
    float qrel[3] = {};
    for (int c8 = 0; c8 < 8; c8++) {
        const uint4 qv = *(const uint4*)&qb[qoff + c8 * 8];
        float q8[8];
        unpack8(qv, q8);
        #pragma unroll
        for (int t = 0; t < 6; t++) {
            float4 f = *(const float4*)(relbase + c8 * 24 + t * 4);
            int b = t * 4;
            qrel[(b    ) % 3] += q8[(b    ) / 3] * f.x;
            qrel[(b + 1) % 3] += q8[(b + 1) / 3] * f.y;
            qrel[(b + 2) % 3] += q8[(b + 2) / 3] * f.z;
            qrel[(b + 3) % 3] += q8[(b + 3) / 3] * f.w;
        }
        #pragma unroll
        for (int ij = 0; ij < 9; ij++) {
            if (inb & (1u << ij)) {
                uint4 kv = *(const uint4*)&kvb[ij * 2368 + koff + c8 * 8];
                sc[ij] = dot8bf(qv, kv, sc[ij]);
            }
        }
    }
    #pragma unroll
    for (int ij = 0; ij < 9; ij++) {
        int idx = (e_th < 4) ? (ij / 3) : (ij % 3);
        sc[ij] += qrel[idx];
    }

    float mx = sc[0];
    #pragma unroll
    for (int ij = 1; ij < 9; ij++) mx = fmaxf(mx, sc[ij]);
    mx = fmaxf(mx, __shfl_xor(mx, 1)); mx = fmaxf(mx, __shfl_xor(mx, 2)); mx = fmaxf(mx, __shfl_xor(mx, 4));
    float sum = 0.f;
    #pragma unroll
    for (int ij = 0; ij < 9; ij++) { sc[ij] = __expf(sc[ij] - mx); sum += sc[ij]; }
    sum += __shfl_xor(sum, 1); sum += __shfl_xor(sum, 2); sum += __shfl_xor(sum, 4);
    const float rinv = 1.f / sum;
    #pragma unroll
    for (int ij = 0; ij < 9; ij++) attn_s[row][e_th * 9 + ij] = sc[ij] * rinv;
    __syncthreads();   // QK reads + attn writes complete

    // ---- stage V (overwrites kvb) ----
    #pragma unroll
    for (int ij = 0; ij < 9; ij++)
        if (inb & (1u << ij))
            *(uint4*)&kvb[ij * 2368 + soff] =
                *(const uint4*)(vt + (nimg + npix[ij]) * 2048 + c_s);
    __syncthreads();

    // ---- AV: wave = m, lane = (g, d) -> V reads broadcast-merge ----
    const int m_av = tid >> 6, l = tid & 63;
    const int g_av = l >> 3, d0 = (l & 7) << 3;
    const int arow = m_av * 8 + g_av;
    const int voff = m_av * 72 + d0;
    float acc[8] = {};
    for (int ij = 0; ij < 9; ij++) {
        if (!(inb & (1u << ij))) continue;
        #pragma unroll
        for (int e = 0; e < 8; e++) {
            const float a = attn_s[arow][e * 9 + ij];
            uint4 vv = *(const uint4*)&kvb[ij * 2368 + e * 296 + voff];
            float v8[8];
            unpack8(vv, v8);
            #pragma unroll
            for (int u = 0; u < 8; u++) acc[u] += a * v8[u];
        }
    }
    const int c0 = g_av * 256 + m_av * 64 + d0;
    st4bf(av + (nimg + p) * 2048 + c0, acc);
    st4bf(av + (nimg + p) * 2048 + c0 + 4, acc + 4);
}

// ---------------- LN over d=64 of A+B; scramble-contiguous write ----------------
__global__ __launch_bounds__(256) void ln_kernel(
    const void* __restrict__ A, int aF32, const void* __restrict__ B, int bF32,
    const float* __restrict__ gamma, const float* __restrict__ beta,
    void* __restrict__ out, int outF32) {
    __shared__ float s[64][68];
    __shared__ float red[2][4][64];
    __shared__ float mu_s[64], rs_s[64], gam[64], bet[64];
    const int tid = threadIdx.x;
    const int pt = blockIdx.x, m = blockIdx.y, ng = blockIdx.z;
    const int n = ng >> 3, g = ng & 7;
    const int p0 = pt << 6;
    if (tid < 64) { gam[tid] = gamma[tid]; bet[tid] = beta[tid]; }

    const int sd = tid >> 2, sp = (tid & 3) << 4;
    {
        const size_t base = (size_t)((n * 8 + g) * 256 + m * 64 + sd) * 1024 + p0 + sp;
        #pragma unroll
        for (int half = 0; half < 2; half++) {
            float a8[8], b8[8];
            if (aF32) ld8f((const float*)A + base + half * 8, a8);
            else      ld8bf((const u16*)A + base + half * 8, a8);
            if (bF32) ld8f((const float*)B + base + half * 8, b8);
            else      ld8bf((const u16*)B + base + half * 8, b8);
            #pragma unroll
            for (int u = 0; u < 8; u++) s[sd][sp + half * 8 + u] = a8[u] + b8[u];
        }
    }
    __syncthreads();
    const int rp = tid & 63, rq = tid >> 6;
    float sm = 0.f, sq = 0.f;
    #pragma unroll
    for (int u = 0; u < 16; u++) { float v = s[rq * 16 + u][rp]; sm += v; sq += v * v; }
    red[0][rq][rp] = sm; red[1][rq][rp] = sq;
    __syncthreads();
    if (tid < 64) {
        float s2 = red[0][0][tid] + red[0][1][tid] + red[0][2][tid] + red[0][3][tid];
        float q2 = red[1][0][tid] + red[1][1][tid] + red[1][2][tid] + red[1][3][tid];
        float mu = s2 * (1.f / 64.f);
        float var = q2 * (1.f / 64.f) - mu * mu;
        mu_s[tid] = mu; rs_s[tid] = rsqrtf(var + 1e-5f);
    }
    __syncthreads();
    const int op = tid >> 2, od = (tid & 3) << 4;
    const float mu = mu_s[op], rs = rs_s[op];
    const size_t obase = (size_t)n * 2097152 + (size_t)(p0 + op) * 2048 + m * 512 + g * 64 + od;
    #pragma unroll
    for (int q4 = 0; q4 < 4; q4++) {
        float v4[4];
        #pragma unroll
        for (int u = 0; u < 4; u++) {
            int d = od + q4 * 4 + u;
            v4[u] = (s[d][op] - mu) * rs * gam[d] + bet[d];
        }
        if (outF32) {
            float4 f4; f4.x = v4[0]; f4.y = v4[1]; f4.z = v4[2]; f4.w = v4[3];
            *(float4*)((float*)out + obase + q4 * 4) = f4;
        } else {
            st4bf((u16*)out + obase + q4 * 4, v4);
        }
    }
}

extern "C" void kernel_launch(void* const* d_in, const int* in_sizes, int n_in,
                              void* d_out, int out_size, void* d_ws, size_t ws_size,
                              hipStream_t stream) {
    const float* x   = (const float*)d_in[0];
    const float* wq  = (const float*)d_in[1];
    const float* wk  = (const float*)d_in[2];
    const float* wv  = (const float*)d_in[3];
    const float* hm  = (const float*)d_in[4];
    const float* wm  = (const float*)d_in[5];
    const float* wc  = (const float*)d_in[6];
    const float* bc  = (const float*)d_in[7];
    const float* wf1 = (const float*)d_in[8];
    const float* bf1 = (const float*)d_in[9];
    const float* wf2 = (const float*)d_in[10];
    const float* bf2w = (const float*)d_in[11];
    const float* g1  = (const float*)d_in[12];
    const float* b1  = (const float*)d_in[13];
    const float* g2  = (const float*)d_in[14];
    const float* b2  = (const float*)d_in[15];
    char* ws = (char*)d_ws;
    u16* bufQ = (u16*)d_out;                     // bf16 scratch in d_out: q -> av -> ffn hidden
    u16* bufK = (u16*)(ws);                      // k -> y2 -> f
    u16* bufV = (u16*)(ws + 16777216);           // v -> y3

    const dim3 gg(8, 2, 32), gb(256);
    gemm_kernel<0, 0, 0><<<gg, gb, 0, stream>>>(wq, x, nullptr, bufQ);
    gemm_kernel<0, 0, 0><<<gg, gb, 0, stream>>>(wk, x, nullptr, bufK);
    gemm_kernel<0, 0, 0><<<gg, gb, 0, stream>>>(wv, x, nullptr, bufV);
    attn_kernel<<<dim3(1024, 4), gb, 0, stream>>>(bufQ, bufK, bufV, hm, wm, bufQ);
    gemm_kernel<2, 1, 0><<<gg, gb, 0, stream>>>(wc, bufQ, bc, bufK);
    ln_kernel<<<dim3(16, 4, 32), gb, 0, stream>>>(x, 1, bufK, 0, g1, b1, bufV, 0);
    gemm_kernel<1, 1, 1><<<gg, gb, 0, stream>>>(wf1, bufV, bf1, bufQ);
    gemm_kernel<1, 1, 0><<<gg, gb, 0, stream>>>(wf2, bufQ, bf2w, bufK);
    ln_kernel<<<dim3(16, 4, 32), gb, 0, stream>>>(bufV, 0, bufK, 0, g2, b2, d_out, 1);
}

// Round 9
// 398.297 us; speedup vs baseline: 1.6146x; 1.0616x over previous
//
#include <hip/hip_runtime.h>

// ConvMGSA on MI355X. Inputs/outputs FLOAT32; intermediates bf16.
// N=4 G=8 CIN=COUT=256 K=3 M=4 D=64 H=W=32 HW=1024.
//
// R9: (1) attn LDS: attn_s overlaid on q buffer -> 52KB -> 3 blocks/CU.
//     (2) x pre-cast to bf16 in d_out's upper half (free 16.8MB scratch);
//         QKV + LN1 read bf16 x (halves their fetch).
//     (3) i-major B staging: v_perm pair-pack + 8 ds_write_b32 (was 16 u16).
// Buffers: d_out[0:16.8M]=Q chain (q->av->hidden), d_out[16.8M:33.5M]=xb,
//          ws[0:16M]=K chain (k->y2->f), ws[16M:32M]=V chain (v->y3).

typedef unsigned short u16;
typedef unsigned int u32;
typedef __attribute__((ext_vector_type(8))) short bf16x8;
typedef __attribute__((ext_vector_type(4))) float f32x4;

__device__ __forceinline__ u32 fbits(float f) { u32 x; __builtin_memcpy(&x, &f, 4); return x; }
__device__ __forceinline__ float bf2f(u32 v) {
    u32 x = v << 16; float f; __builtin_memcpy(&f, &x, 4); return f;
}
__device__ __forceinline__ u16 f2bf(float f) {
    u32 x = fbits(f);
    u32 r = x + 0x7fffu + ((x >> 16) & 1u);
    return (u16)(r >> 16);
}
__device__ __forceinline__ u32 pack2bf(float a, float b) {
    return __builtin_amdgcn_perm(fbits(b) + 0x8000u, fbits(a) + 0x8000u, 0x07060302u);
}

__device__ __forceinline__ void unpack8(uint4 u, float* o) {
    o[0] = bf2f(u.x & 0xffff); o[1] = bf2f(u.x >> 16);
    o[2] = bf2f(u.y & 0xffff); o[3] = bf2f(u.y >> 16);
    o[4] = bf2f(u.z & 0xffff); o[5] = bf2f(u.z >> 16);
    o[6] = bf2f(u.w & 0xffff); o[7] = bf2f(u.w >> 16);
}
__device__ __forceinline__ void ld8bf(const u16* p, float* o) { unpack8(*(const uint4*)p, o); }
__device__ __forceinline__ void ld8f(const float* p, float* o) {
    float4 a = *(const float4*)p, b = *(const float4*)(p + 4);
    o[0] = a.x; o[1] = a.y; o[2] = a.z; o[3] = a.w;
    o[4] = b.x; o[5] = b.y; o[6] = b.z; o[7] = b.w;
}
__device__ __forceinline__ void st4bf(u16* p, const float* v) {
    ushort4 s; s.x = f2bf(v[0]); s.y = f2bf(v[1]); s.z = f2bf(v[2]); s.w = f2bf(v[3]);
    *(ushort4*)p = s;
}

#if defined(__has_builtin)
#if __has_builtin(__builtin_amdgcn_fdot2_f32_bf16)
#define HAVE_BFDOT 1
#endif
#endif
#ifdef HAVE_BFDOT
typedef __attribute__((ext_vector_type(2))) __bf16 v2bf;
__device__ __forceinline__ float dot2bf(u32 a, u32 b, float c) {
    return __builtin_amdgcn_fdot2_f32_bf16(__builtin_bit_cast(v2bf, a),
                                           __builtin_bit_cast(v2bf, b), c, false);
}
#else
__device__ __forceinline__ float dot2bf(u32 a, u32 b, float c) {
    return c + bf2f(a & 0xffff) * bf2f(b & 0xffff) + bf2f(a >> 16) * bf2f(b >> 16);
}
#endif
__device__ __forceinline__ float dot8bf(uint4 a, uint4 b, float c) {
    c = dot2bf(a.x, b.x, c); c = dot2bf(a.y, b.y, c);
    c = dot2bf(a.z, b.z, c); c = dot2bf(a.w, b.w, c);
    return c;
}

// ---------------- x f32 -> bf16 cast (8.39M elems) ----------------
__global__ __launch_bounds__(256) void xcast_kernel(const float* __restrict__ x,
                                                    u16* __restrict__ xb) {
    const size_t i = ((size_t)blockIdx.x * 256 + threadIdx.x) * 8;
    float4 a = *(const float4*)(x + i), b = *(const float4*)(x + i + 4);
    uint4 o;
    o.x = pack2bf(a.x, a.y); o.y = pack2bf(a.z, a.w);
    o.z = pack2bf(b.x, b.y); o.w = pack2bf(b.z, b.w);
    *(uint4*)(xb + i) = o;
}

// ================= MFMA GEMM: C[o][p] = sum_i W[g][o][i] * B[i][p] =================
// BMODE: 1=bf16 i-major (pair-pack transpose staging), 2=bf16 pixel-major
// OUTMODE: 0=bf16 pixel-major [p][g*256+o], 1=bf16 channel-major +bias(+relu)
template<int BMODE, int OUTMODE, int RELU>
__global__ __launch_bounds__(256) void gemm_kernel(
    const float* __restrict__ A, const void* __restrict__ B,
    const float* __restrict__ bias, u16* __restrict__ out) {
    __shared__ __align__(16) char smem[OUTMODE == 1 ? 64 * 132 * 4 : 20480];
    u16* Al = (u16*)smem;              // [128][40] bf16  (o, k)
    u16* Bl = (u16*)(smem + 10240);    // [128][40] bf16  (p, k)
    float* Cl = (float*)smem;          // [64][132] f32   (epilogue transpose)

    const int tid = threadIdx.x;
    const int pt = blockIdx.x, ot = blockIdx.y, ng = blockIdx.z;
    const int n = ng >> 3, g = ng & 7;
    const int p0 = pt << 7, o0 = ot << 7;
    const float* Ag = A + (size_t)g * 65536;

    const int l = tid & 63, w = tid >> 6;
    const int mq = w >> 1;
    const int mw = mq << 6, nw = (w & 1) << 6;
    const int lrow = l & 15, lk = (l >> 4) << 3;

    f32x4 acc[4][4];
    #pragma unroll
    for (int i = 0; i < 4; i++)
        #pragma unroll
        for (int j = 0; j < 4; j++) acc[i][j] = (f32x4){0.f, 0.f, 0.f, 0.f};

    for (int k0 = 0; k0 < 256; k0 += 32) {
        {   // stage A: f32 weights, rows k-contiguous, pack2bf
            const int r = tid >> 1, cb = (tid & 1) << 4;
            const float* src = Ag + (size_t)(o0 + r) * 256 + k0 + cb;
            u32* dst = (u32*)&Al[r * 40 + cb];
            #pragma unroll
            for (int q = 0; q < 4; q++) {
                float4 f = *(const float4*)(src + q * 4);
                dst[q * 2]     = pack2bf(f.x, f.y);
                dst[q * 2 + 1] = pack2bf(f.z, f.w);
            }
        }
        if (BMODE == 2) {
            const int r = tid >> 1, cb = (tid & 1) << 4;
            const u16* src = (const u16*)B + (size_t)(n * 1024 + p0 + r) * 2048 + g * 256 + k0 + cb;
            *(uint4*)&Bl[r * 40 + cb]     = *(const uint4*)src;
            *(uint4*)&Bl[r * 40 + cb + 8] = *(const uint4*)(src + 8);
        } else {
            // bf16 i-major: load rows k, k+1; v_perm pair-pack; 8 b32 writes
            const int kp = tid & 15, po = tid >> 4;
            const u16* src = (const u16*)B + (size_t)(ng * 256 + k0 + 2 * kp) * 1024 + p0 + po * 8;
            uint4 r0 = *(const uint4*)src;
            uint4 r1 = *(const uint4*)(src + 1024);
            u32 a0[4] = { r0.x, r0.y, r0.z, r0.w };
            u32 a1[4] = { r1.x, r1.y, r1.z, r1.w };
            #pragma unroll
            for (int j = 0; j < 4; j++) {
                u32 w0 = __builtin_amdgcn_perm(a1[j], a0[j], 0x05040100u);  // p=2j
                u32 w1 = __builtin_amdgcn_perm(a1[j], a0[j], 0x07060302u);  // p=2j+1
                *(u32*)&Bl[(po * 8 + 2 * j    ) * 40 + 2 * kp] = w0;
                *(u32*)&Bl[(po * 8 + 2 * j + 1) * 40 + 2 * kp] = w1;
            }
        }
        __syncthreads();
        bf16x8 af[4], bfg[4];
        #pragma unroll
        for (int i = 0; i < 4; i++) af[i]  = *(const bf16x8*)&Al[(mw + i * 16 + lrow) * 40 + lk];
        #pragma unroll
        for (int j = 0; j < 4; j++) bfg[j] = *(const bf16x8*)&Bl[(nw + j * 16 + lrow) * 40 + lk];
        #pragma unroll
        for (int i = 0; i < 4; i++)
            #pragma unroll
            for (int j = 0; j < 4; j++)
                acc[i][j] = __builtin_amdgcn_mfma_f32_16x16x32_bf16(af[i], bfg[j], acc[i][j], 0, 0, 0);
        __syncthreads();
    }

    if (OUTMODE == 0) {
        #pragma unroll
        for (int i = 0; i < 4; i++) {
            const int orow = o0 + mw + i * 16 + ((l >> 4) << 2);
            #pragma unroll
            for (int j = 0; j < 4; j++) {
                const int p = p0 + nw + j * 16 + lrow;
                float v4[4] = { acc[i][j].x, acc[i][j].y, acc[i][j].z, acc[i][j].w };
                st4bf(out + (size_t)(n * 1024 + p) * 2048 + g * 256 + orow, v4);
            }
        }
    } else {
        for (int ph = 0; ph < 2; ph++) {
            __syncthreads();
            if (mq == ph) {
                #pragma unroll
                for (int i = 0; i < 4; i++) {
                    const int rl = i * 16 + ((l >> 4) << 2);
                    #pragma unroll
                    for (int j = 0; j < 4; j++) {
                        const int c = nw + j * 16 + lrow;
                        Cl[(rl    ) * 132 + c] = acc[i][j].x;
                        Cl[(rl + 1) * 132 + c] = acc[i][j].y;
                        Cl[(rl + 2) * 132 + c] = acc[i][j].z;
                        Cl[(rl + 3) * 132 + c] = acc[i][j].w;
                    }
                }
            }
            __syncthreads();
            {
                const int row = tid >> 2, pc = (tid & 3) << 5;
                const int og = o0 + ph * 64 + row;
                const float bb = bias ? bias[g * 256 + og] : 0.f;
                u32 pk[16];
                #pragma unroll
                for (int q = 0; q < 8; q++) {
                    float4 f = *(const float4*)&Cl[row * 132 + pc + q * 4];
                    float a0 = f.x + bb, a1 = f.y + bb, a2 = f.z + bb, a3 = f.w + bb;
                    if (RELU) {
                        a0 = fmaxf(a0, 0.f); a1 = fmaxf(a1, 0.f);
                        a2 = fmaxf(a2, 0.f); a3 = fmaxf(a3, 0.f);
                    }
                    pk[q * 2]     = pack2bf(a0, a1);
                    pk[q * 2 + 1] = pack2bf(a2, a3);
                }
                u16* dst = out + (size_t)(ng * 256 + og) * 1024 + p0 + pc;
                #pragma unroll
                for (int q = 0; q < 4; q++) *(uint4*)(dst + q * 8) = *(uint4*)&pk[q * 4];
            }
        }
    }
}

// ---------------- attention: one block per (n, pixel), LDS-staged ----------------
// kvb: [ij][e][m][72] u16 (strides ij 2368, e 296, m 72) = 42.6KB.
// qau: union { q [g][m][72] u16 (4736B) ; attn_f [32][73] f32 (9344B) } -> 52KB total.
__global__ __launch_bounds__(256) void attn_kernel(
    const u16* __restrict__ qt, const u16* __restrict__ kt,
    const u16* __restrict__ vt, const float* __restrict__ hm,
    const float* __restrict__ wm, u16* __restrict__ av) {
    __shared__ __align__(16) u16 kvb[9 * 2368];
    __shared__ __align__(16) u16 qau[4672];
    u16* qb = qau;
    float* attn_f = (float*)qau;
    const int tid = threadIdx.x;
    const int p = blockIdx.x, n = blockIdx.y;
    const int ph = p >> 5, pw = p & 31;
    const size_t nimg = (size_t)n * 1024;

    int npix[9]; unsigned inb = 0;
    #pragma unroll
    for (int ij = 0; ij < 9; ij++) {
        int hs = ph + ij / 3 - 1, ws = pw + ij % 3 - 1;
        npix[ij] = hs * 32 + ws;
        if (((unsigned)hs < 32u) && ((unsigned)ws < 32u)) inb |= (1u << ij);
    }

    const int c_s = tid << 3;
    const int soff = (tid >> 5) * 296 + ((tid >> 3) & 3) * 72 + (tid & 7) * 8;

    // ---- stage q + K ----
    *(uint4*)&qb[soff] = *(const uint4*)(qt + (nimg + p) * 2048 + c_s);
    #pragma unroll
    for (int ij = 0; ij < 9; ij++)
        if (inb & (1u << ij))
            *(uint4*)&kvb[ij * 2368 + soff] =
                *(const uint4*)(kt + (nimg + npix[ij]) * 2048 + c_s);
    __syncthreads();

    // ---- QK: thread (row=m*8+g, e) ----
    const int e_th = tid & 7;
    const int row = tid >> 3, g_th = row & 7, m_th = row >> 3;
    const int qoff = g_th * 296 + m_th * 72;
    const int koff = e_th * 296 + m_th * 72;
    const int cbase = e_th * 256 + m_th * 64;
    const float* relbase = (e_th < 4) ? (hm + (size_t)cbase * 3)
                                      : (wm + (size_t)(cbase - 1024) * 3);

    float sc[9] = {};
    float qrel[3] = {};
    for (int c8 = 0; c8 < 8; c8++) {
        const uint4 qv = *(const uint4*)&qb[qoff + c8 * 8];
        float q8[8];
        unpack8(qv, q8);
        #pragma unroll
        for (int t = 0; t < 6; t++) {
            float4 f = *(const float4*)(relbase + c8 * 24 + t * 4);
            int b = t * 4;
            qrel[(b    ) % 3] += q8[(b    ) / 3] * f.x;
            qrel[(b + 1) % 3] += q8[(b + 1) / 3] * f.y;
            qrel[(b + 2) % 3] += q8[(b + 2) / 3] * f.z;
            qrel[(b + 3) % 3] += q8[(b + 3) / 3] * f.w;
        }
        #pragma unroll
        for (int ij = 0; ij < 9; ij++) {
            if (inb & (1u << ij)) {
                uint4 kv = *(const uint4*)&kvb[ij * 2368 + koff + c8 * 8];
                sc[ij] = dot8bf(qv, kv, sc[ij]);
            }
        }
    }
    #pragma unroll
    for (int ij = 0; ij < 9; ij++) {
        int idx = (e_th < 4) ? (ij / 3) : (ij % 3);
        sc[ij] += qrel[idx];
    }

    float mx = sc[0];
    #pragma unroll
    for (int ij = 1; ij < 9; ij++) mx = fmaxf(mx, sc[ij]);
    mx = fmaxf(mx, __shfl_xor(mx, 1)); mx = fmaxf(mx, __shfl_xor(mx, 2)); mx = fmaxf(mx, __shfl_xor(mx, 4));
    float sum = 0.f;
    #pragma unroll
    for (int ij = 0; ij < 9; ij++) { sc[ij] = __expf(sc[ij] - mx); sum += sc[ij]; }
    sum += __shfl_xor(sum, 1); sum += __shfl_xor(sum, 2); sum += __shfl_xor(sum, 4);
    const float rinv = 1.f / sum;

    __syncthreads();   // all qb/kvb reads done; qau and kvb may be overwritten

    #pragma unroll
    for (int ij = 0; ij < 9; ij++) attn_f[row * 73 + e_th * 9 + ij] = sc[ij] * rinv;
    // ---- stage V (overwrites kvb) ----
    #pragma unroll
    for (int ij = 0; ij < 9; ij++)
        if (inb & (1u << ij))
            *(uint4*)&kvb[ij * 2368 + soff] =
                *(const uint4*)(vt + (nimg + npix[ij]) * 2048 + c_s);
    __syncthreads();

    // ---- AV: wave = m, lane = (g, d) -> V reads broadcast-merge ----
    const int m_av = tid >> 6, l = tid & 63;
    const int g_av = l >> 3, d0 = (l & 7) << 3;
    const int arow = m_av * 8 + g_av;
    const int voff = m_av * 72 + d0;
    float acc[8] = {};
    for (int ij = 0; ij < 9; ij++) {
        if (!(inb & (1u << ij))) continue;
        #pragma unroll
        for (int e = 0; e < 8; e++) {
            const float a = attn_f[arow * 73 + e * 9 + ij];
            uint4 vv = *(const uint4*)&kvb[ij * 2368 + e * 296 + voff];
            float v8[8];
            unpack8(vv, v8);
            #pragma unroll
            for (int u = 0; u < 8; u++) acc[u] += a * v8[u];
        }
    }
    const int c0 = g_av * 256 + m_av * 64 + d0;
    st4bf(av + (nimg + p) * 2048 + c0, acc);
    st4bf(av + (nimg + p) * 2048 + c0 + 4, acc + 4);
}

// ---------------- LN over d=64 of A+B; scramble-contiguous write ----------------
__global__ __launch_bounds__(256) void ln_kernel(
    const void* __restrict__ A, int aF32, const void* __restrict__ B, int bF32,
    const float* __restrict__ gamma, const float* __restrict__ beta,
    void* __restrict__ out, int outF32) {
    __shared__ float s[64][68];
    __shared__ float red[2][4][64];
    __shared__ float mu_s[64], rs_s[64], gam[64], bet[64];
    const int tid = threadIdx.x;
    const int pt = blockIdx.x, m = blockIdx.y, ng = blockIdx.z;
    const int n = ng >> 3, g = ng & 7;
    const int p0 = pt << 6;
    if (tid < 64) { gam[tid] = gamma[tid]; bet[tid] = beta[tid]; }

    const int sd = tid >> 2, sp = (tid & 3) << 4;
    {
        const size_t base = (size_t)((n * 8 + g) * 256 + m * 64 + sd) * 1024 + p0 + sp;
        #pragma unroll
        for (int half = 0; half < 2; half++) {
            float a8[8], b8[8];
            if (aF32) ld8f((const float*)A + base + half * 8, a8);
            else      ld8bf((const u16*)A + base + half * 8, a8);
            if (bF32) ld8f((const float*)B + base + half * 8, b8);
            else      ld8bf((const u16*)B + base + half * 8, b8);
            #pragma unroll
            for (int u = 0; u < 8; u++) s[sd][sp + half * 8 + u] = a8[u] + b8[u];
        }
    }
    __syncthreads();
    const int rp = tid & 63, rq = tid >> 6;
    float sm = 0.f, sq = 0.f;
    #pragma unroll
    for (int u = 0; u < 16; u++) { float v = s[rq * 16 + u][rp]; sm += v; sq += v * v; }
    red[0][rq][rp] = sm; red[1][rq][rp] = sq;
    __syncthreads();
    if (tid < 64) {
        float s2 = red[0][0][tid] + red[0][1][tid] + red[0][2][tid] + red[0][3][tid];
        float q2 = red[1][0][tid] + red[1][1][tid] + red[1][2][tid] + red[1][3][tid];
        float mu = s2 * (1.f / 64.f);
        float var = q2 * (1.f / 64.f) - mu * mu;
        mu_s[tid] = mu; rs_s[tid] = rsqrtf(var + 1e-5f);
    }
    __syncthreads();
    const int op = tid >> 2, od = (tid & 3) << 4;
    const float mu = mu_s[op], rs = rs_s[op];
    const size_t obase = (size_t)n * 2097152 + (size_t)(p0 + op) * 2048 + m * 512 + g * 64 + od;
    #pragma unroll
    for (int q4 = 0; q4 < 4; q4++) {
        float v4[4];
        #pragma unroll
        for (int u = 0; u < 4; u++) {
            int d = od + q4 * 4 + u;
            v4[u] = (s[d][op] - mu) * rs * gam[d] + bet[d];
        }
        if (outF32) {
            float4 f4; f4.x = v4[0]; f4.y = v4[1]; f4.z = v4[2]; f4.w = v4[3];
            *(float4*)((float*)out + obase + q4 * 4) = f4;
        } else {
            st4bf((u16*)out + obase + q4 * 4, v4);
        }
    }
}

extern "C" void kernel_launch(void* const* d_in, const int* in_sizes, int n_in,
                              void* d_out, int out_size, void* d_ws, size_t ws_size,
                              hipStream_t stream) {
    const float* x   = (const float*)d_in[0];
    const float* wq  = (const float*)d_in[1];
    const float* wk  = (const float*)d_in[2];
    const float* wv  = (const float*)d_in[3];
    const float* hm  = (const float*)d_in[4];
    const float* wm  = (const float*)d_in[5];
    const float* wc  = (const float*)d_in[6];
    const float* bc  = (const float*)d_in[7];
    const float* wf1 = (const float*)d_in[8];
    const float* bf1 = (const float*)d_in[9];
    const float* wf2 = (const float*)d_in[10];
    const float* bf2w = (const float*)d_in[11];
    const float* g1  = (const float*)d_in[12];
    const float* b1  = (const float*)d_in[13];
    const float* g2  = (const float*)d_in[14];
    const float* b2  = (const float*)d_in[15];
    char* ws = (char*)d_ws;
    u16* bufQ = (u16*)d_out;                     // d_out lower half: q -> av -> hidden
    u16* xb   = bufQ + 8388608;                  // d_out upper half: bf16 x (dead before LN2)
    u16* bufK = (u16*)(ws);                      // k -> y2 -> f
    u16* bufV = (u16*)(ws + 16777216);           // v -> y3

    const dim3 gg(8, 2, 32), gb(256);
    xcast_kernel<<<dim3(4096), gb, 0, stream>>>(x, xb);
    gemm_kernel<1, 0, 0><<<gg, gb, 0, stream>>>(wq, xb, nullptr, bufQ);
    gemm_kernel<1, 0, 0><<<gg, gb, 0, stream>>>(wk, xb, nullptr, bufK);
    gemm_kernel<1, 0, 0><<<gg, gb, 0, stream>>>(wv, xb, nullptr, bufV);
    attn_kernel<<<dim3(1024, 4), gb, 0, stream>>>(bufQ, bufK, bufV, hm, wm, bufQ);
    gemm_kernel<2, 1, 0><<<gg, gb, 0, stream>>>(wc, bufQ, bc, bufK);
    ln_kernel<<<dim3(16, 4, 32), gb, 0, stream>>>(xb, 0, bufK, 0, g1, b1, bufV, 0);
    gemm_kernel<1, 1, 1><<<gg, gb, 0, stream>>>(wf1, bufV, bf1, bufQ);
    gemm_kernel<1, 1, 0><<<gg, gb, 0, stream>>>(wf2, bufQ, bf2w, bufK);
    ln_kernel<<<dim3(16, 4, 32), gb, 0, stream>>>(bufV, 0, bufK, 0, g2, b2, d_out, 1);
}